// Round 6
// baseline (971.941 us; speedup 1.0000x reference)
//
#include <hip/hip_runtime.h>
#include <hip/hip_bf16.h>

// BayesianKAN: 3 layers of  out[b,o] = sum_{i,k} B-spline-basis(x[b,i])[k] * cm[o,i,k]
// == GEMM (M=8192, N=OUT, K=IN*16) with generated A-operand, plus KL scalar.
// Numerics (validated R4/R5): f16 MFMA; L0 2-term A-split, L1/L2 1-term.
// R6: barrier-free wave-autonomous K-loop. Each wave stages its OWN 64-row A
// subtile in private LDS (producer==consumer, in-order DS pipe -> NO
// __syncthreads anywhere). Basis rows composed in registers (cndmask select),
// written as 8 ds_write_b128 with XOR chunk swizzle (<=2-way, free). B frags
// global->VGPR from pre-swizzled layout, double-buffered one kstep ahead
// (full-iteration latency slack). R5 counters: MFMA-pipe busy ~= f16 floor,
// ~90us of barrier/latency stall -- this removes the barriers entirely.

typedef __attribute__((ext_vector_type(8))) _Float16 f16x8;  // 8 f16 in 4 VGPRs
typedef __attribute__((ext_vector_type(4))) float float4v;   // MFMA accumulator
typedef unsigned short ushort_t;

__device__ __forceinline__ ushort_t f2h(float f) {
  _Float16 h = (_Float16)f;                 // RTE
  return *(ushort_t*)&h;
}
__device__ __forceinline__ float h2f(ushort_t u) {
  return (float)*(_Float16*)&u;
}

// Cubic B-spline (n_basis=16, clamped uniform knots: 13 cells of width 1/13).
__device__ __forceinline__ void bspline_w4(float x, int& k0, float w[4]) {
  const float XMAX = 1.0f - 1e-6f;
  float xe = fminf(fmaxf(x, 0.0f), XMAX);
  int cell = (int)(xe * 13.0f);
  cell = cell > 12 ? 12 : cell;
  k0 = cell;
  int j = cell + 3;                 // knot span, 3..15
  const float s = 1.0f / 13.0f;
  int cjm2 = max(j - 5, 0);
  int cjm1 = max(j - 4, 0);
  int cj   = j - 3;
  int cj1  = j - 2;
  int cj2  = min(j - 1, 13);
  int cj3  = min(j, 13);
  float tjm2 = cjm2 * s, tjm1 = cjm1 * s, tj = cj * s;
  float tj1 = cj1 * s, tj2 = cj2 * s, tj3 = cj3 * s;
  float left1 = xe - tj, left2 = xe - tjm1, left3 = xe - tjm2;
  float right1 = tj1 - xe, right2 = tj2 - xe, right3 = tj3 - xe;
#define INV3(d) ((d) == 1 ? 13.0f : ((d) == 2 ? 6.5f : (13.0f / 3.0f)))
  float i10 = INV3(cj1 - cj);
  float i20 = INV3(cj1 - cjm1), i21 = INV3(cj2 - cj);
  float i30 = INV3(cj1 - cjm2), i31 = INV3(cj2 - cjm1), i32 = INV3(cj3 - cj);
#undef INV3
  float temp = i10;
  float N0 = right1 * temp;
  float N1 = left1 * temp;
  temp = N0 * i20;
  N0 = right1 * temp;
  float saved = left2 * temp;
  temp = N1 * i21;
  N1 = saved + right2 * temp;
  float N2 = left1 * temp;
  temp = N0 * i30;
  N0 = right1 * temp;
  saved = left3 * temp;
  temp = N1 * i31;
  N1 = saved + right2 * temp;
  saved = left2 * temp;
  temp = N2 * i32;
  N2 = saved + right3 * temp;
  float N3 = left1 * temp;
  w[0] = N0; w[1] = N1; w[2] = N2; w[3] = N3;
}

// Build the 16-f16 basis row (8 dwords) for one feature in registers:
// taps w[0..3] at f16 positions k0..k0+3, zeros elsewhere.
__device__ __forceinline__ void compose16(const float w[4], int k0, unsigned u[8]) {
  unsigned h0 = f2h(w[0]), h1 = f2h(w[1]), h2 = f2h(w[2]), h3 = f2h(w[3]);
  int e = k0 >> 1;
  bool odd = (k0 & 1) != 0;
  unsigned a = odd ? (h0 << 16) : (h0 | (h1 << 16));
  unsigned b = odd ? (h1 | (h2 << 16)) : (h2 | (h3 << 16));
  unsigned c = odd ? (unsigned)h3 : 0u;
#pragma unroll
  for (int j = 0; j < 8; ++j)
    u[j] = (j == e) ? a : (j == e + 1) ? b : (j == e + 2) ? c : 0u;
}

__device__ __forceinline__ void load_bfrags(const ushort_t* __restrict__ Bsw,
                                            int tbase, int KC, int k, int lane,
                                            f16x8 bf[2][4]) {
#pragma unroll
  for (int ks = 0; ks < 2; ++ks)
#pragma unroll
    for (int nt = 0; nt < 4; ++nt) {
      size_t eoff = (((size_t)(tbase + nt)) * KC + (size_t)k * 8 + ks * 4) * 128
                    + lane * 8;
      bf[ks][nt] = *(const f16x8*)&Bsw[eoff];
    }
}

// Fused basis-gen + GEMM, barrier-free. Block 128x128, 4 waves 2x2, wave tile
// 64x64 (4x4 frags of f32_16x16x32_f16), BK=64 (4 feats). blockIdx.z = split-K;
// partials atomicAdd into pre-zeroed outp.
template <bool SPLIT_A>
__global__ __launch_bounds__(256, 2) void kan_layer(
    const float* __restrict__ act, const ushort_t* __restrict__ Bsw,
    float* __restrict__ outp, int IN, int OUT) {
  const int K = IN * 16;
  const int KC = K >> 3;                       // k-chunks of 8
  __shared__ ushort_t Ah[4 * 64 * 64];         // 4 wave-private 8KB regions
  __shared__ ushort_t Al[SPLIT_A ? 4 * 64 * 64 : 1];

  const int tid = threadIdx.x;
  const int lane = tid & 63;
  const int wv = tid >> 6;
  const int wm = wv >> 1, wn = wv & 1;
  const int quad = lane >> 4, l15 = lane & 15;
  const int b0 = blockIdx.x * 128;
  const int n0 = blockIdx.y * 128;
  const int tbase = (n0 >> 4) + wn * 4;        // B row-tile base for this wave
  ushort_t* Awh = &Ah[wv * 4096];
  ushort_t* Awl = SPLIT_A ? &Al[wv * 4096] : nullptr;
  const int grow = b0 + wm * 64 + lane;        // this lane's activation row
  const int sw = (lane & 7);                   // XOR swizzle key for writes

  float4v acc[4][4];
#pragma unroll
  for (int a = 0; a < 4; a++)
#pragma unroll
    for (int b = 0; b < 4; b++) acc[a][b] = (float4v)0.0f;

  const int nsteps = K / 64;
  const int chunk = nsteps / gridDim.z;
  const int kbeg = blockIdx.z * chunk;
  const int kend = kbeg + chunk;

  f16x8 bf[2][2][4];
  float4 xv = *(const float4*)&act[(size_t)grow * IN + kbeg * 4];
  load_bfrags(Bsw, tbase, KC, kbeg, lane, bf[0]);
  int cur = 0;

  for (int k = kbeg; k < kend; ++k) {
    // ---- issue next-kstep loads first (full iteration of latency slack) ----
    float4 xn = xv;
    if (k + 1 < kend) {
      xn = *(const float4*)&act[(size_t)grow * IN + (k + 1) * 4];
      load_bfrags(Bsw, tbase, KC, k + 1, lane, bf[cur ^ 1]);
    }

    // ---- stage this lane's A row: 4 feats, register-composed, b128 writes ----
#pragma unroll
    for (int f = 0; f < 4; ++f) {
      float xf = (f == 0) ? xv.x : (f == 1) ? xv.y : (f == 2) ? xv.z : xv.w;
      int k0; float w[4];
      bspline_w4(xf, k0, w);
      unsigned u[8];
      compose16(w, k0, u);
      int s0 = ((2 * f) ^ sw) * 8;
      int s1 = ((2 * f + 1) ^ sw) * 8;
      *(uint4*)&Awh[lane * 64 + s0] = make_uint4(u[0], u[1], u[2], u[3]);
      *(uint4*)&Awh[lane * 64 + s1] = make_uint4(u[4], u[5], u[6], u[7]);
      if (SPLIT_A) {
        float wl[4];
#pragma unroll
        for (int t = 0; t < 4; ++t) wl[t] = w[t] - h2f(f2h(w[t]));
        compose16(wl, k0, u);
        *(uint4*)&Awl[lane * 64 + s0] = make_uint4(u[0], u[1], u[2], u[3]);
        *(uint4*)&Awl[lane * 64 + s1] = make_uint4(u[4], u[5], u[6], u[7]);
      }
    }

    // ---- read own-wave fragments (in-order DS pipe: no barrier needed) ----
#pragma unroll
    for (int ks = 0; ks < 2; ++ks) {
      f16x8 ah[4], al[4];
#pragma unroll
      for (int mt = 0; mt < 4; ++mt) {
        int off = (mt * 16 + l15) * 64 + (((ks * 4 + quad) ^ (l15 & 7)) * 8);
        ah[mt] = *(const f16x8*)&Awh[off];
        if (SPLIT_A) al[mt] = *(const f16x8*)&Awl[off];
      }
#pragma unroll
      for (int mt = 0; mt < 4; ++mt)
#pragma unroll
        for (int nt = 0; nt < 4; ++nt) {
          if (SPLIT_A)
            acc[mt][nt] = __builtin_amdgcn_mfma_f32_16x16x32_f16(al[mt], bf[cur][ks][nt], acc[mt][nt], 0, 0, 0);
          acc[mt][nt] = __builtin_amdgcn_mfma_f32_16x16x32_f16(ah[mt], bf[cur][ks][nt], acc[mt][nt], 0, 0, 0);
        }
    }
    xv = xn;
    cur ^= 1;
  }

  // ---- epilogue: C/D layout col=lane&15, row=quad*4+reg; split-K atomics ----
#pragma unroll
  for (int mt = 0; mt < 4; ++mt)
#pragma unroll
    for (int nt = 0; nt < 4; ++nt) {
      int col = n0 + wn * 64 + nt * 16 + l15;
#pragma unroll
      for (int r = 0; r < 4; ++r) {
        int row = b0 + wm * 64 + mt * 16 + quad * 4 + r;
        atomicAdd(&outp[(size_t)row * OUT + col], acc[mt][nt][r]);
      }
    }
}

// KL accumulation + f16 conversion + fragment-order swizzle, one pass over cm/lv.
// Group = 8 consecutive k of one output row o: dest Bsw[o/16][k/8][o%16][8].
__global__ __launch_bounds__(256) void kl_convert(
    const float* __restrict__ cm, const float* __restrict__ lv,
    ushort_t* __restrict__ bsw, int G /* = IN*2 groups per row */,
    long long ngroups, float* __restrict__ klout) {
  long long i = (long long)blockIdx.x * blockDim.x + threadIdx.x;
  const long long stride = (long long)gridDim.x * blockDim.x;
  float s = 0.0f;
  for (; i < ngroups; i += stride) {
    int o = (int)(i / G);
    int kc = (int)(i - (long long)o * G);
    const float* cp = &cm[i * 8];
    const float* lp = &lv[i * 8];
    unsigned pk[4];
#pragma unroll
    for (int t = 0; t < 4; ++t) {
      float c0 = cp[2 * t], c1 = cp[2 * t + 1];
      float l0 = lp[2 * t], l1 = lp[2 * t + 1];
      pk[t] = (unsigned)f2h(c0) | ((unsigned)f2h(c1) << 16);
      s += 0.5f * (__expf(l0) + c0 * c0 - 1.0f - l0);
      s += 0.5f * (__expf(l1) + c1 * c1 - 1.0f - l1);
    }
    uint4 v; v.x = pk[0]; v.y = pk[1]; v.z = pk[2]; v.w = pk[3];
    size_t doff = (((size_t)(o >> 4) * G + kc) * 16 + (o & 15)) * 8;
    *(uint4*)&bsw[doff] = v;
  }
#pragma unroll
  for (int off = 32; off > 0; off >>= 1) s += __shfl_down(s, off, 64);
  __shared__ float red[4];
  int wvi = threadIdx.x >> 6;
  if ((threadIdx.x & 63) == 0) red[wvi] = s;
  __syncthreads();
  if (threadIdx.x == 0)
    atomicAdd(klout, red[0] + red[1] + red[2] + red[3]);
}

extern "C" void kernel_launch(void* const* d_in, const int* in_sizes, int n_in,
                              void* d_out, int out_size, void* d_ws, size_t ws_size,
                              hipStream_t stream) {
  const float* x   = (const float*)d_in[0];
  const float* cm0 = (const float*)d_in[1];
  const float* lv0 = (const float*)d_in[2];
  const float* cm1 = (const float*)d_in[3];
  const float* lv1 = (const float*)d_in[4];
  const float* cm2 = (const float*)d_in[5];
  const float* lv2 = (const float*)d_in[6];

  float* out = (float*)d_out;                       // (8192*256) out + 1 KL
  float* klp = out + (size_t)8192 * 256;

  // ws layout (48 MB): acts 2x16MB, swizzled f16 weights 16MB
  char* ws = (char*)d_ws;
  float*    act1 = (float*)(ws);                               // 8192*512 f32
  float*    act2 = (float*)(ws + ((size_t)16 << 20));          // 8192*512 f32
  ushort_t* b0sw = (ushort_t*)(ws + ((size_t)32 << 20));       // 512*256*16 f16
  ushort_t* b1sw = (ushort_t*)(ws + ((size_t)36 << 20));       // 512*512*16 f16
  ushort_t* b2sw = (ushort_t*)(ws + ((size_t)44 << 20));       // 256*512*16 f16

  // zero split-K accumulation targets (act1+act2 contiguous; d_out incl KL)
  hipMemsetAsync(ws, 0, (size_t)32 << 20, stream);
  hipMemsetAsync(d_out, 0, (size_t)out_size * sizeof(float), stream);

  kl_convert<<<2048, 256, 0, stream>>>(cm0, lv0, b0sw, 256 * 2, 512LL * 256 * 2, klp);
  kl_convert<<<2048, 256, 0, stream>>>(cm1, lv1, b1sw, 512 * 2, 512LL * 512 * 2, klp);
  kl_convert<<<2048, 256, 0, stream>>>(cm2, lv2, b2sw, 512 * 2, 256LL * 512 * 2, klp);

  // 1024 blocks/layer; LDS: L0 64KB (2 blk/CU), L1/L2 32KB
  kan_layer<true ><<<dim3(64, 4, 4), 256, 0, stream>>>(x,    b0sw, act1, 256, 512);
  kan_layer<false><<<dim3(64, 4, 4), 256, 0, stream>>>(act1, b1sw, act2, 512, 512);
  kan_layer<false><<<dim3(64, 2, 8), 256, 0, stream>>>(act2, b2sw, out,  512, 256);
}

// Round 7
// 633.917 us; speedup vs baseline: 1.5332x; 1.5332x over previous
//
#include <hip/hip_runtime.h>
#include <hip/hip_bf16.h>

// BayesianKAN: 3 layers of  out[b,o] = sum_{i,k} B-spline-basis(x[b,i])[k] * cm[o,i,k]
// == GEMM (M=8192, N=OUT, K=IN*16) with generated A-operand, plus KL scalar.
// Numerics (validated R4/R5): f16 MFMA; L0 2-term A-split, L1/L2 1-term.
// R6 structure (validated): barrier-free wave-autonomous K-loop; wave-private
// A subtile in LDS, register-composed basis rows, XOR swizzle -> 0 conflicts.
// R6 BUG (fixed in R7): B double-buffer bf[2][..] indexed by runtime 'cur'
// -> compiler put it in scratch (HBM): WRITE_SIZE 1.1GB, VGPR=64, 7% MfmaUtil.
// R7: K-loop unrolled by 2 with statically-named ping-pong buffers bfA/bfB so
// all indices are compile-time constants -> B stays in VGPRs.

typedef __attribute__((ext_vector_type(8))) _Float16 f16x8;  // 8 f16 in 4 VGPRs
typedef __attribute__((ext_vector_type(4))) float float4v;   // MFMA accumulator
typedef unsigned short ushort_t;

__device__ __forceinline__ ushort_t f2h(float f) {
  _Float16 h = (_Float16)f;                 // RTE
  return *(ushort_t*)&h;
}
__device__ __forceinline__ float h2f(ushort_t u) {
  return (float)*(_Float16*)&u;
}

// Cubic B-spline (n_basis=16, clamped uniform knots: 13 cells of width 1/13).
__device__ __forceinline__ void bspline_w4(float x, int& k0, float w[4]) {
  const float XMAX = 1.0f - 1e-6f;
  float xe = fminf(fmaxf(x, 0.0f), XMAX);
  int cell = (int)(xe * 13.0f);
  cell = cell > 12 ? 12 : cell;
  k0 = cell;
  int j = cell + 3;                 // knot span, 3..15
  const float s = 1.0f / 13.0f;
  int cjm2 = max(j - 5, 0);
  int cjm1 = max(j - 4, 0);
  int cj   = j - 3;
  int cj1  = j - 2;
  int cj2  = min(j - 1, 13);
  int cj3  = min(j, 13);
  float tjm2 = cjm2 * s, tjm1 = cjm1 * s, tj = cj * s;
  float tj1 = cj1 * s, tj2 = cj2 * s, tj3 = cj3 * s;
  float left1 = xe - tj, left2 = xe - tjm1, left3 = xe - tjm2;
  float right1 = tj1 - xe, right2 = tj2 - xe, right3 = tj3 - xe;
#define INV3(d) ((d) == 1 ? 13.0f : ((d) == 2 ? 6.5f : (13.0f / 3.0f)))
  float i10 = INV3(cj1 - cj);
  float i20 = INV3(cj1 - cjm1), i21 = INV3(cj2 - cj);
  float i30 = INV3(cj1 - cjm2), i31 = INV3(cj2 - cjm1), i32 = INV3(cj3 - cj);
#undef INV3
  float temp = i10;
  float N0 = right1 * temp;
  float N1 = left1 * temp;
  temp = N0 * i20;
  N0 = right1 * temp;
  float saved = left2 * temp;
  temp = N1 * i21;
  N1 = saved + right2 * temp;
  float N2 = left1 * temp;
  temp = N0 * i30;
  N0 = right1 * temp;
  saved = left3 * temp;
  temp = N1 * i31;
  N1 = saved + right2 * temp;
  saved = left2 * temp;
  temp = N2 * i32;
  N2 = saved + right3 * temp;
  float N3 = left1 * temp;
  w[0] = N0; w[1] = N1; w[2] = N2; w[3] = N3;
}

// Build the 16-f16 basis row (8 dwords) for one feature in registers:
// taps w[0..3] at f16 positions k0..k0+3, zeros elsewhere.
__device__ __forceinline__ void compose16(const float w[4], int k0, unsigned u[8]) {
  unsigned h0 = f2h(w[0]), h1 = f2h(w[1]), h2 = f2h(w[2]), h3 = f2h(w[3]);
  int e = k0 >> 1;
  bool odd = (k0 & 1) != 0;
  unsigned a = odd ? (h0 << 16) : (h0 | (h1 << 16));
  unsigned b = odd ? (h1 | (h2 << 16)) : (h2 | (h3 << 16));
  unsigned c = odd ? (unsigned)h3 : 0u;
#pragma unroll
  for (int j = 0; j < 8; ++j)
    u[j] = (j == e) ? a : (j == e + 1) ? b : (j == e + 2) ? c : 0u;
}

// Fused basis-gen + GEMM, barrier-free. Block 128x128, 4 waves 2x2, wave tile
// 64x64 (4x4 frags of f32_16x16x32_f16), BK=64 (4 feats). blockIdx.z = split-K;
// partials atomicAdd into pre-zeroed outp. K-loop unrolled x2 (ping-pong B).
template <bool SPLIT_A>
__global__ __launch_bounds__(256, 2) void kan_layer(
    const float* __restrict__ act, const ushort_t* __restrict__ Bsw,
    float* __restrict__ outp, int IN, int OUT) {
  const int K = IN * 16;
  const int KC = K >> 3;                       // k-chunks of 8
  __shared__ ushort_t Ah[4 * 64 * 64];         // 4 wave-private 8KB regions
  __shared__ ushort_t Al[SPLIT_A ? 4 * 64 * 64 : 1];

  const int tid = threadIdx.x;
  const int lane = tid & 63;
  const int wv = tid >> 6;
  const int wm = wv >> 1, wn = wv & 1;
  const int quad = lane >> 4, l15 = lane & 15;
  const int b0 = blockIdx.x * 128;
  const int n0 = blockIdx.y * 128;
  const int tbase = (n0 >> 4) + wn * 4;        // B row-tile base for this wave
  ushort_t* Awh = &Ah[wv * 4096];
  ushort_t* Awl = SPLIT_A ? &Al[wv * 4096] : nullptr;
  const int grow = b0 + wm * 64 + lane;        // this lane's activation row
  const int sw = (lane & 7);                   // XOR swizzle key for writes

  float4v acc[4][4];
#pragma unroll
  for (int a = 0; a < 4; a++)
#pragma unroll
    for (int b = 0; b < 4; b++) acc[a][b] = (float4v)0.0f;

  const int nsteps = K / 64;
  const int chunk = nsteps / gridDim.z;        // even for all layer configs
  const int kbeg = blockIdx.z * chunk;
  const int kend = kbeg + chunk;

  f16x8 bfA[2][4], bfB[2][4];

#define LOAD_BF(dst, kk)                                                      \
  {                                                                           \
    _Pragma("unroll") for (int ks = 0; ks < 2; ++ks)                          \
        _Pragma("unroll") for (int nt = 0; nt < 4; ++nt) {                    \
      size_t eoff =                                                           \
          (((size_t)(tbase + nt)) * KC + (size_t)(kk) * 8 + ks * 4) * 128 +   \
          lane * 8;                                                           \
      dst[ks][nt] = *(const f16x8*)&Bsw[eoff];                                \
    }                                                                         \
  }

  // one kstep of compute: stage this lane's A row (4 feats) + 32 MFMAs
#define DO_STEP(xvv, bfv)                                                     \
  {                                                                           \
    _Pragma("unroll") for (int f = 0; f < 4; ++f) {                           \
      float xf = (f == 0) ? xvv.x : (f == 1) ? xvv.y : (f == 2) ? xvv.z       \
                                                                : xvv.w;      \
      int k0; float w[4];                                                     \
      bspline_w4(xf, k0, w);                                                  \
      unsigned u[8];                                                          \
      compose16(w, k0, u);                                                    \
      int s0 = ((2 * f) ^ sw) * 8;                                            \
      int s1 = ((2 * f + 1) ^ sw) * 8;                                        \
      *(uint4*)&Awh[lane * 64 + s0] = make_uint4(u[0], u[1], u[2], u[3]);     \
      *(uint4*)&Awh[lane * 64 + s1] = make_uint4(u[4], u[5], u[6], u[7]);     \
      if (SPLIT_A) {                                                          \
        float wl[4];                                                          \
        _Pragma("unroll") for (int t = 0; t < 4; ++t) wl[t] =                 \
            w[t] - h2f(f2h(w[t]));                                            \
        compose16(wl, k0, u);                                                 \
        *(uint4*)&Awl[lane * 64 + s0] = make_uint4(u[0], u[1], u[2], u[3]);   \
        *(uint4*)&Awl[lane * 64 + s1] = make_uint4(u[4], u[5], u[6], u[7]);   \
      }                                                                       \
    }                                                                         \
    _Pragma("unroll") for (int ks = 0; ks < 2; ++ks) {                        \
      f16x8 ah[4], al[4];                                                     \
      _Pragma("unroll") for (int mt = 0; mt < 4; ++mt) {                      \
        int off = (mt * 16 + l15) * 64 + (((ks * 4 + quad) ^ (l15 & 7)) * 8); \
        ah[mt] = *(const f16x8*)&Awh[off];                                    \
        if (SPLIT_A) al[mt] = *(const f16x8*)&Awl[off];                       \
      }                                                                       \
      _Pragma("unroll") for (int mt = 0; mt < 4; ++mt)                        \
          _Pragma("unroll") for (int nt = 0; nt < 4; ++nt) {                  \
        if (SPLIT_A)                                                          \
          acc[mt][nt] = __builtin_amdgcn_mfma_f32_16x16x32_f16(               \
              al[mt], bfv[ks][nt], acc[mt][nt], 0, 0, 0);                     \
        acc[mt][nt] = __builtin_amdgcn_mfma_f32_16x16x32_f16(                 \
            ah[mt], bfv[ks][nt], acc[mt][nt], 0, 0, 0);                       \
      }                                                                       \
    }                                                                         \
  }

  float4 xv = *(const float4*)&act[(size_t)grow * IN + kbeg * 4];
  LOAD_BF(bfA, kbeg);

  for (int k = kbeg; k < kend; k += 2) {
    // prefetch k+1 into B-buffer (k+1 < kend guaranteed: chunk is even)
    float4 x1 = *(const float4*)&act[(size_t)grow * IN + (k + 1) * 4];
    LOAD_BF(bfB, k + 1);
    DO_STEP(xv, bfA);

    // prefetch k+2 into A-buffer
    float4 x2 = xv;
    if (k + 2 < kend) {
      x2 = *(const float4*)&act[(size_t)grow * IN + (k + 2) * 4];
      LOAD_BF(bfA, k + 2);
    }
    DO_STEP(x1, bfB);
    xv = x2;
  }
#undef LOAD_BF
#undef DO_STEP

  // ---- epilogue: C/D layout col=lane&15, row=quad*4+reg; split-K atomics ----
#pragma unroll
  for (int mt = 0; mt < 4; ++mt)
#pragma unroll
    for (int nt = 0; nt < 4; ++nt) {
      int col = n0 + wn * 64 + nt * 16 + l15;
#pragma unroll
      for (int r = 0; r < 4; ++r) {
        int row = b0 + wm * 64 + mt * 16 + quad * 4 + r;
        atomicAdd(&outp[(size_t)row * OUT + col], acc[mt][nt][r]);
      }
    }
}

// KL accumulation + f16 conversion + fragment-order swizzle, one pass over cm/lv.
// Group = 8 consecutive k of one output row o: dest Bsw[o/16][k/8][o%16][8].
__global__ __launch_bounds__(256) void kl_convert(
    const float* __restrict__ cm, const float* __restrict__ lv,
    ushort_t* __restrict__ bsw, int G /* = IN*2 groups per row */,
    long long ngroups, float* __restrict__ klout) {
  long long i = (long long)blockIdx.x * blockDim.x + threadIdx.x;
  const long long stride = (long long)gridDim.x * blockDim.x;
  float s = 0.0f;
  for (; i < ngroups; i += stride) {
    int o = (int)(i / G);
    int kc = (int)(i - (long long)o * G);
    const float* cp = &cm[i * 8];
    const float* lp = &lv[i * 8];
    unsigned pk[4];
#pragma unroll
    for (int t = 0; t < 4; ++t) {
      float c0 = cp[2 * t], c1 = cp[2 * t + 1];
      float l0 = lp[2 * t], l1 = lp[2 * t + 1];
      pk[t] = (unsigned)f2h(c0) | ((unsigned)f2h(c1) << 16);
      s += 0.5f * (__expf(l0) + c0 * c0 - 1.0f - l0);
      s += 0.5f * (__expf(l1) + c1 * c1 - 1.0f - l1);
    }
    uint4 v; v.x = pk[0]; v.y = pk[1]; v.z = pk[2]; v.w = pk[3];
    size_t doff = (((size_t)(o >> 4) * G + kc) * 16 + (o & 15)) * 8;
    *(uint4*)&bsw[doff] = v;
  }
#pragma unroll
  for (int off = 32; off > 0; off >>= 1) s += __shfl_down(s, off, 64);
  __shared__ float red[4];
  int wvi = threadIdx.x >> 6;
  if ((threadIdx.x & 63) == 0) red[wvi] = s;
  __syncthreads();
  if (threadIdx.x == 0)
    atomicAdd(klout, red[0] + red[1] + red[2] + red[3]);
}

extern "C" void kernel_launch(void* const* d_in, const int* in_sizes, int n_in,
                              void* d_out, int out_size, void* d_ws, size_t ws_size,
                              hipStream_t stream) {
  const float* x   = (const float*)d_in[0];
  const float* cm0 = (const float*)d_in[1];
  const float* lv0 = (const float*)d_in[2];
  const float* cm1 = (const float*)d_in[3];
  const float* lv1 = (const float*)d_in[4];
  const float* cm2 = (const float*)d_in[5];
  const float* lv2 = (const float*)d_in[6];

  float* out = (float*)d_out;                       // (8192*256) out + 1 KL
  float* klp = out + (size_t)8192 * 256;

  // ws layout (48 MB): acts 2x16MB, swizzled f16 weights 16MB
  char* ws = (char*)d_ws;
  float*    act1 = (float*)(ws);                               // 8192*512 f32
  float*    act2 = (float*)(ws + ((size_t)16 << 20));          // 8192*512 f32
  ushort_t* b0sw = (ushort_t*)(ws + ((size_t)32 << 20));       // 512*256*16 f16
  ushort_t* b1sw = (ushort_t*)(ws + ((size_t)36 << 20));       // 512*512*16 f16
  ushort_t* b2sw = (ushort_t*)(ws + ((size_t)44 << 20));       // 256*512*16 f16

  // zero split-K accumulation targets (act1+act2 contiguous; d_out incl KL)
  hipMemsetAsync(ws, 0, (size_t)32 << 20, stream);
  hipMemsetAsync(d_out, 0, (size_t)out_size * sizeof(float), stream);

  kl_convert<<<2048, 256, 0, stream>>>(cm0, lv0, b0sw, 256 * 2, 512LL * 256 * 2, klp);
  kl_convert<<<2048, 256, 0, stream>>>(cm1, lv1, b1sw, 512 * 2, 512LL * 512 * 2, klp);
  kl_convert<<<2048, 256, 0, stream>>>(cm2, lv2, b2sw, 512 * 2, 256LL * 512 * 2, klp);

  // 1024 blocks/layer; LDS: L0 64KB (2 blk/CU), L1/L2 32KB
  kan_layer<true ><<<dim3(64, 4, 4), 256, 0, stream>>>(x,    b0sw, act1, 256, 512);
  kan_layer<false><<<dim3(64, 4, 4), 256, 0, stream>>>(act1, b1sw, act2, 512, 512);
  kan_layer<false><<<dim3(64, 2, 8), 256, 0, stream>>>(act2, b2sw, out,  512, 256);
}

// Round 8
// 515.474 us; speedup vs baseline: 1.8855x; 1.2298x over previous
//
#include <hip/hip_runtime.h>
#include <hip/hip_bf16.h>

// BayesianKAN: 3 layers of  out[b,o] = sum_{i,k} B-spline-basis(x[b,i])[k] * cm[o,i,k]
// == GEMM (M=8192, N=OUT, K=IN*16) with generated A-operand, plus KL scalar.
// Numerics (validated R4-R7): f16 MFMA; L0 2-term A-split, L1/L2 1-term.
// R8: pipe-ratio rebalance. Per-SIMD: one 16x16x32 MFMA ~= 19.4 cyc; wave
// 64x128 tile -> 43.7 FLOP per LDS-frag-byte so the 85-128 B/cyc LDS pipe
// roughly matches the MFMA pipe (R4/R5/R7 were LDS- or VALU-bound by 3-5x).
// Block 128x256 (4 waves 2x2, acc 4x8). B via global_load_lds into frag-layout
// LDS (linear 1KB windows; reads base+lane*16, 0 conflicts, static). A staged
// cooperatively (2 splines/thread/kstep, no duplication) into frag-layout LDS
// (2x b128/unit). 2 barriers/kstep, 2 blocks/CU overlap them.

typedef __attribute__((ext_vector_type(8))) _Float16 f16x8;  // 8 f16 in 4 VGPRs
typedef __attribute__((ext_vector_type(4))) float float4v;   // MFMA accumulator
typedef unsigned short ushort_t;

#define GLOBAL_AS __attribute__((address_space(1)))
#define LDS_AS __attribute__((address_space(3)))

__device__ __forceinline__ void async_copy16(const void* g, void* l) {
  __builtin_amdgcn_global_load_lds((const GLOBAL_AS unsigned int*)g,
                                   (LDS_AS unsigned int*)l, 16, 0, 0);
}

__device__ __forceinline__ ushort_t f2h(float f) {
  _Float16 h = (_Float16)f;                 // RTE
  return *(ushort_t*)&h;
}
__device__ __forceinline__ float h2f(ushort_t u) {
  return (float)*(_Float16*)&u;
}

// Cubic B-spline (n_basis=16, clamped uniform knots: 13 cells of width 1/13).
__device__ __forceinline__ void bspline_w4(float x, int& k0, float w[4]) {
  const float XMAX = 1.0f - 1e-6f;
  float xe = fminf(fmaxf(x, 0.0f), XMAX);
  int cell = (int)(xe * 13.0f);
  cell = cell > 12 ? 12 : cell;
  k0 = cell;
  int j = cell + 3;                 // knot span, 3..15
  const float s = 1.0f / 13.0f;
  int cjm2 = max(j - 5, 0);
  int cjm1 = max(j - 4, 0);
  int cj   = j - 3;
  int cj1  = j - 2;
  int cj2  = min(j - 1, 13);
  int cj3  = min(j, 13);
  float tjm2 = cjm2 * s, tjm1 = cjm1 * s, tj = cj * s;
  float tj1 = cj1 * s, tj2 = cj2 * s, tj3 = cj3 * s;
  float left1 = xe - tj, left2 = xe - tjm1, left3 = xe - tjm2;
  float right1 = tj1 - xe, right2 = tj2 - xe, right3 = tj3 - xe;
#define INV3(d) ((d) == 1 ? 13.0f : ((d) == 2 ? 6.5f : (13.0f / 3.0f)))
  float i10 = INV3(cj1 - cj);
  float i20 = INV3(cj1 - cjm1), i21 = INV3(cj2 - cj);
  float i30 = INV3(cj1 - cjm2), i31 = INV3(cj2 - cjm1), i32 = INV3(cj3 - cj);
#undef INV3
  float temp = i10;
  float N0 = right1 * temp;
  float N1 = left1 * temp;
  temp = N0 * i20;
  N0 = right1 * temp;
  float saved = left2 * temp;
  temp = N1 * i21;
  N1 = saved + right2 * temp;
  float N2 = left1 * temp;
  temp = N0 * i30;
  N0 = right1 * temp;
  saved = left3 * temp;
  temp = N1 * i31;
  N1 = saved + right2 * temp;
  saved = left2 * temp;
  temp = N2 * i32;
  N2 = saved + right3 * temp;
  float N3 = left1 * temp;
  w[0] = N0; w[1] = N1; w[2] = N2; w[3] = N3;
}

// Build the 16-f16 basis row (8 dwords) for one feature in registers.
__device__ __forceinline__ void compose16(const float w[4], int k0, unsigned u[8]) {
  unsigned h0 = f2h(w[0]), h1 = f2h(w[1]), h2 = f2h(w[2]), h3 = f2h(w[3]);
  int e = k0 >> 1;
  bool odd = (k0 & 1) != 0;
  unsigned a = odd ? (h0 << 16) : (h0 | (h1 << 16));
  unsigned b = odd ? (h1 | (h2 << 16)) : (h2 | (h3 << 16));
  unsigned c = odd ? (unsigned)h3 : 0u;
#pragma unroll
  for (int j = 0; j < 8; ++j)
    u[j] = (j == e) ? a : (j == e + 1) ? b : (j == e + 2) ? c : 0u;
}

// Block 128(M) x 256(N), BK=64. 4 waves 2x2; wave tile 64x128 (4x8 frags of
// f32_16x16x32_f16). A and B both in MFMA-fragment-layout LDS.
// blockIdx.z = split-K; partials atomicAdd into pre-zeroed outp.
template <bool SPLIT_A>
__global__ __launch_bounds__(256, 2) void kan_layer(
    const float* __restrict__ act, const ushort_t* __restrict__ Bsw,
    float* __restrict__ outp, int IN, int OUT) {
  const int K = IN * 16;
  const int KC = K >> 3;                       // k-chunks of 8
  __shared__ ushort_t Bt[32 * 512];            // 32 KB: 32 windows [nt16][kc2]
  __shared__ ushort_t Ahi[16 * 512];           // 16 KB: 16 blocks [mt8][kc2]
  __shared__ ushort_t Alo[SPLIT_A ? 16 * 512 : 1];

  const int tid = threadIdx.x;
  const int lane = tid & 63;
  const int wv = tid >> 6;
  const int wm = wv >> 1, wn = wv & 1;
  const int quad = lane >> 4, l15 = lane & 15;
  const int b0 = blockIdx.x * 128;
  const int n0 = blockIdx.y * 256;
  const int tbase = n0 >> 4;                   // global B n-tile base

  float4v acc[4][8];
#pragma unroll
  for (int a = 0; a < 4; a++)
#pragma unroll
    for (int b = 0; b < 8; b++) acc[a][b] = (float4v)0.0f;

  const int sr = tid & 127;                    // staging row 0..127
  const int sf = (tid >> 7) * 2;               // staging feats sf, sf+1

  const int nsteps = K / 64;
  const int chunk = nsteps / gridDim.z;        // exact for all configs
  const int kbeg = blockIdx.z * chunk;
  const int kend = kbeg + chunk;

  for (int kstep = kbeg; kstep < kend; ++kstep) {
    // ---- pre-barrier: activation load + spline eval + compose (no LDS) ----
    const float2 xv = *(const float2*)&act[(size_t)(b0 + sr) * IN + kstep * 4 + sf];
    unsigned uh0[8], uh1[8], ul0[8], ul1[8];
    {
      int k0; float w[4];
      bspline_w4(xv.x, k0, w);
      compose16(w, k0, uh0);
      if (SPLIT_A) {
        float wl[4];
#pragma unroll
        for (int t = 0; t < 4; ++t) wl[t] = w[t] - h2f(f2h(w[t]));
        compose16(wl, k0, ul0);
      }
      bspline_w4(xv.y, k0, w);
      compose16(w, k0, uh1);
      if (SPLIT_A) {
        float wl[4];
#pragma unroll
        for (int t = 0; t < 4; ++t) wl[t] = w[t] - h2f(f2h(w[t]));
        compose16(wl, k0, ul1);
      }
    }

    __syncthreads();   // previous iteration's fragment reads complete

    // ---- B: 32 async 1KB windows global->LDS (frag-contiguous source) ----
#pragma unroll
    for (int j = 0; j < 8; ++j) {
      int w = wv * 8 + j;                      // window = nt*2 + kc
      int nt = w >> 1, kc = w & 1;
      size_t goff = ((size_t)(tbase + nt) * KC + (size_t)kstep * 8 + kc * 4) * 128
                    + lane * 8;
      async_copy16(&Bsw[goff], &Bt[w * 512 + lane * 8]);
    }

    // ---- A: write 2 frag-layout b128 per (row,feat) unit ----
#pragma unroll
    for (int f = 0; f < 2; ++f) {
      const unsigned* uh = f == 0 ? uh0 : uh1;
      int ff = sf + f;
      int base = ((sr >> 4) * 2 + (ff >> 1)) * 512 + (ff & 1) * 256 + (sr & 15) * 8;
      *(uint4*)&Ahi[base]       = make_uint4(uh[0], uh[1], uh[2], uh[3]);
      *(uint4*)&Ahi[base + 128] = make_uint4(uh[4], uh[5], uh[6], uh[7]);
      if (SPLIT_A) {
        const unsigned* ul = f == 0 ? ul0 : ul1;
        *(uint4*)&Alo[base]       = make_uint4(ul[0], ul[1], ul[2], ul[3]);
        *(uint4*)&Alo[base + 128] = make_uint4(ul[4], ul[5], ul[6], ul[7]);
      }
    }

    __syncthreads();   // A visible + B vmcnt drained

    // ---- fragment reads (static, conflict-free) + MFMA ----
#pragma unroll
    for (int ks = 0; ks < 2; ++ks) {
      f16x8 ah[4], al[4], bh[8];
#pragma unroll
      for (int mt = 0; mt < 4; ++mt) {
        int fb = ((wm * 4 + mt) * 2 + ks) * 512 + lane * 8;
        ah[mt] = *(const f16x8*)&Ahi[fb];
        if (SPLIT_A) al[mt] = *(const f16x8*)&Alo[fb];
      }
#pragma unroll
      for (int nt = 0; nt < 8; ++nt)
        bh[nt] = *(const f16x8*)&Bt[((wn * 8 + nt) * 2 + ks) * 512 + lane * 8];
#pragma unroll
      for (int mt = 0; mt < 4; ++mt)
#pragma unroll
        for (int nt = 0; nt < 8; ++nt) {
          if (SPLIT_A)
            acc[mt][nt] = __builtin_amdgcn_mfma_f32_16x16x32_f16(al[mt], bh[nt], acc[mt][nt], 0, 0, 0);
          acc[mt][nt] = __builtin_amdgcn_mfma_f32_16x16x32_f16(ah[mt], bh[nt], acc[mt][nt], 0, 0, 0);
        }
    }
  }

  // ---- epilogue: C/D layout col=lane&15, row=quad*4+reg; split-K atomics ----
#pragma unroll
  for (int mt = 0; mt < 4; ++mt)
#pragma unroll
    for (int nt = 0; nt < 8; ++nt) {
      int col = n0 + wn * 128 + nt * 16 + l15;
#pragma unroll
      for (int r = 0; r < 4; ++r) {
        int row = b0 + wm * 64 + mt * 16 + quad * 4 + r;
        atomicAdd(&outp[(size_t)row * OUT + col], acc[mt][nt][r]);
      }
    }
}

// KL accumulation + f16 conversion + fragment-order swizzle, one pass over cm/lv.
// Group = 8 consecutive k of one output row o: dest Bsw[o/16][k/8][o%16][8].
__global__ __launch_bounds__(256) void kl_convert(
    const float* __restrict__ cm, const float* __restrict__ lv,
    ushort_t* __restrict__ bsw, int G /* = IN*2 groups per row */,
    long long ngroups, float* __restrict__ klout) {
  long long i = (long long)blockIdx.x * blockDim.x + threadIdx.x;
  const long long stride = (long long)gridDim.x * blockDim.x;
  float s = 0.0f;
  for (; i < ngroups; i += stride) {
    int o = (int)(i / G);
    int kc = (int)(i - (long long)o * G);
    const float* cp = &cm[i * 8];
    const float* lp = &lv[i * 8];
    unsigned pk[4];
#pragma unroll
    for (int t = 0; t < 4; ++t) {
      float c0 = cp[2 * t], c1 = cp[2 * t + 1];
      float l0 = lp[2 * t], l1 = lp[2 * t + 1];
      pk[t] = (unsigned)f2h(c0) | ((unsigned)f2h(c1) << 16);
      s += 0.5f * (__expf(l0) + c0 * c0 - 1.0f - l0);
      s += 0.5f * (__expf(l1) + c1 * c1 - 1.0f - l1);
    }
    uint4 v; v.x = pk[0]; v.y = pk[1]; v.z = pk[2]; v.w = pk[3];
    size_t doff = (((size_t)(o >> 4) * G + kc) * 16 + (o & 15)) * 8;
    *(uint4*)&bsw[doff] = v;
  }
#pragma unroll
  for (int off = 32; off > 0; off >>= 1) s += __shfl_down(s, off, 64);
  __shared__ float red[4];
  int wvi = threadIdx.x >> 6;
  if ((threadIdx.x & 63) == 0) red[wvi] = s;
  __syncthreads();
  if (threadIdx.x == 0)
    atomicAdd(klout, red[0] + red[1] + red[2] + red[3]);
}

extern "C" void kernel_launch(void* const* d_in, const int* in_sizes, int n_in,
                              void* d_out, int out_size, void* d_ws, size_t ws_size,
                              hipStream_t stream) {
  const float* x   = (const float*)d_in[0];
  const float* cm0 = (const float*)d_in[1];
  const float* lv0 = (const float*)d_in[2];
  const float* cm1 = (const float*)d_in[3];
  const float* lv1 = (const float*)d_in[4];
  const float* cm2 = (const float*)d_in[5];
  const float* lv2 = (const float*)d_in[6];

  float* out = (float*)d_out;                       // (8192*256) out + 1 KL
  float* klp = out + (size_t)8192 * 256;

  // ws layout (48 MB): acts 2x16MB, swizzled f16 weights 16MB
  char* ws = (char*)d_ws;
  float*    act1 = (float*)(ws);                               // 8192*512 f32
  float*    act2 = (float*)(ws + ((size_t)16 << 20));          // 8192*512 f32
  ushort_t* b0sw = (ushort_t*)(ws + ((size_t)32 << 20));       // 512*256*16 f16
  ushort_t* b1sw = (ushort_t*)(ws + ((size_t)36 << 20));       // 512*512*16 f16
  ushort_t* b2sw = (ushort_t*)(ws + ((size_t)44 << 20));       // 256*512*16 f16

  // zero split-K accumulation targets (act1+act2 contiguous; d_out incl KL)
  hipMemsetAsync(ws, 0, (size_t)32 << 20, stream);
  hipMemsetAsync(d_out, 0, (size_t)out_size * sizeof(float), stream);

  kl_convert<<<2048, 256, 0, stream>>>(cm0, lv0, b0sw, 256 * 2, 512LL * 256 * 2, klp);
  kl_convert<<<2048, 256, 0, stream>>>(cm1, lv1, b1sw, 512 * 2, 512LL * 512 * 2, klp);
  kl_convert<<<2048, 256, 0, stream>>>(cm2, lv2, b2sw, 512 * 2, 256LL * 512 * 2, klp);

  // 512 blocks/layer -> 2 blocks/CU. LDS: L0 64KB, L1/L2 48KB. Atomics 64MB/layer.
  kan_layer<true ><<<dim3(64, 2, 4), 256, 0, stream>>>(x,    b0sw, act1, 256, 512);
  kan_layer<false><<<dim3(64, 2, 4), 256, 0, stream>>>(act1, b1sw, act2, 512, 512);
  kan_layer<false><<<dim3(64, 1, 8), 256, 0, stream>>>(act2, b2sw, out,  512, 256);
}